// Round 8
// baseline (93.052 us; speedup 1.0000x reference)
//
#include <hip/hip_runtime.h>
#include <cstdint>
#include <cstddef>

// B=2, N=M=8192, 3-float points.
#define B_ 2
#define N_ 8192
#define M_ 8192
#define COLSPLIT 16
#define CCHUNK (N_ / COLSPLIT)      // 512 cols per block
#define NTILES (CCHUNK / 32)        // 16 col tiles of 32
#define ROWBLKS (M_ / 128)          // 64 row blocks
#define RBLOCKS ((B_ * M_) / 256)   // 64 reduce blocks

typedef __attribute__((ext_vector_type(8))) short short8;
typedef __attribute__((ext_vector_type(16))) float f32x16;

union FragU { uint4 u; short8 s; };

// round-to-nearest-even f32 -> bf16 bits
__device__ __forceinline__ unsigned bf16r(float f) {
    unsigned u = __float_as_uint(f);
    return ((u + 0x7FFFu + ((u >> 16) & 1u)) >> 16) & 0xFFFFu;
}
#define BF_ONE 0x3F80u

__device__ __forceinline__ unsigned umin_(unsigned a, unsigned b) { return a < b ? a : b; }
__device__ __forceinline__ unsigned long long ullmin_(unsigned long long a, unsigned long long b) { return a < b ? a : b; }

// ---------------------------------------------------------------------------
// Encoder + init. One thread per point (64 blocks x 256 = B*N threads):
//   predB[b,n] = uint4 bf16x8 [-2x,-2y,-2z,1,1,Nh,Nl,0]   (MFMA B operand)
//   refA [b,m] = uint4 bf16x8 [x,y,z,Nh,Nl,1,1,0]         (MFMA A operand)
// plus colminU sentinels (first 4096 threads) and d_out zeroing (thread 0).
// Hoists all norm/packing VALU out of the 2048-block hot kernel.
// ---------------------------------------------------------------------------
__global__ __launch_bounds__(256) void k_init(
    const float* __restrict__ pred_pts,   // [B,N,3]
    const float* __restrict__ ref_pts,    // [B,M,3]
    uint4* __restrict__ predB,            // [B*N]
    uint4* __restrict__ refA,             // [B*M]
    uint4* __restrict__ colminU4,         // [B*N/4] sentinel region
    float* __restrict__ out)              // [3]
{
    const int i = blockIdx.x * 256 + threadIdx.x;   // 0 .. B*N-1

    if (i == 0) { out[0] = 0.f; out[1] = 0.f; out[2] = 0.f; }
    if (i < (B_ * N_) / 4) {
        uint4 v = {0xFFFFFFFFu, 0xFFFFFFFFu, 0xFFFFFFFFu, 0xFFFFFFFFu};
        colminU4[i] = v;
    }

    {   // B operand (pred)
        const float* p = pred_pts + (size_t)i * 3;
        float x = p[0], y = p[1], z = p[2];
        float nrm = x * x + y * y + z * z;
        unsigned nh = bf16r(nrm);
        unsigned nl = bf16r(nrm - __uint_as_float(nh << 16));
        uint4 v;
        v.x = bf16r(-2.f * x) | (bf16r(-2.f * y) << 16);
        v.y = bf16r(-2.f * z) | (BF_ONE << 16);
        v.z = BF_ONE | (nh << 16);
        v.w = nl;                              // slot7 = 0
        predB[i] = v;
    }
    {   // A operand (ref)
        const float* r = ref_pts + (size_t)i * 3;
        float x = r[0], y = r[1], z = r[2];
        float nrm = x * x + y * y + z * z;
        unsigned nh = bf16r(nrm);
        unsigned nl = bf16r(nrm - __uint_as_float(nh << 16));
        uint4 v;
        v.x = bf16r(x) | (bf16r(y) << 16);
        v.y = bf16r(z) | (nh << 16);
        v.z = nl | (BF_ONE << 16);
        v.w = BF_ONE;                          // slot7 = 0
        refA[i] = v;
    }
}

// ---------------------------------------------------------------------------
// MFMA pairwise-d2 kernel. D[m(ref) rows][n(pred) cols], both directions from
// one tile sweep; operands are PRE-ENCODED by k_init (staging = pure uint4
// copy, A-frag = one dwordx4 load). 2 tiles/iter (2 MFMAs in flight); row
// argmin: v_and_or_b32 pack + v_min3_u32 in registers; col min: in-lane fmin
// tree + LDS atomicMin (8 contributors/col, off the critical path).
// Epilogue: rows -> plain per-colsplit stores; cols -> global u32 atomicMin.
// grid = (ROWBLKS, COLSPLIT, B) = (64, 16, 2) = 2048 blocks, 4 waves/SIMD.
// ---------------------------------------------------------------------------
__global__ __launch_bounds__(256, 4) void k_pairs(
    const uint4* __restrict__ predB,          // [B*N] encoded B operands
    const uint4* __restrict__ refA,           // [B*M] encoded A operands
    unsigned long long* __restrict__ rowpart, // [B][COLSPLIT][M] plain stores
    unsigned int* __restrict__ colminU)       // [B*N] sentinel-init
{
    __shared__ uint4 ldsB[CCHUNK + 1];        // [CCHUNK] is the zero slot
    __shared__ unsigned int ldsCol[CCHUNK];

    const int t    = threadIdx.x;
    const int wave = t >> 6;
    const int lane = t & 63;
    const int l31  = lane & 31;
    const int half = lane >> 5;
    const int rowblk  = blockIdx.x;
    const int cs      = blockIdx.y;
    const int colbase = cs * CCHUNK;
    const int b       = blockIdx.z;

    // ---- stage encoded B vectors (pure copy) ----
    #pragma unroll
    for (int i = t; i < CCHUNK; i += 256) {
        ldsB[i] = predB[(size_t)b * N_ + colbase + i];
        ldsCol[i] = 0xFFFFFFFFu;
    }
    if (t == 0) { uint4 z4 = {0, 0, 0, 0}; ldsB[CCHUNK] = z4; }

    // ---- A frag: one dwordx4 load; lanes >= 32 hold the zero K-half ----
    const int rowbase = rowblk * 128 + wave * 32;
    FragU af;
    if (half == 0) af.u = refA[(size_t)b * M_ + rowbase + l31];
    else           { af.u.x = af.u.y = af.u.z = af.u.w = 0; }
    __syncthreads();

    f32x16 zero16 = {};
    unsigned rowbest[16];
    #pragma unroll
    for (int i = 0; i < 16; ++i) rowbest[i] = 0xFFFFFFFFu;

    const int bslot = (half == 0) ? l31 : CCHUNK;   // zero slot for hi half
    const int bstep = (half == 0) ? 32 : 0;

    #pragma unroll 2
    for (int tile = 0; tile < NTILES; tile += 2) {
        FragU b0; b0.u = ldsB[bslot + tile * bstep];
        FragU b1; b1.u = ldsB[bslot + (tile + 1) * bstep];
        f32x16 acc0 = __builtin_amdgcn_mfma_f32_32x32x16_bf16(af.s, b0.s, zero16, 0, 0, 0);
        f32x16 acc1 = __builtin_amdgcn_mfma_f32_32x32x16_bf16(af.s, b1.s, zero16, 0, 0, 0);

        const unsigned lcol0 = (unsigned)(tile * 32 + l31);
        const unsigned lcol1 = lcol0 + 32;
        #pragma unroll
        for (int i = 0; i < 16; ++i) {
            unsigned pk0 = (__float_as_uint(acc0[i]) & 0xFFFFF800u) | lcol0;  // v_and_or_b32
            unsigned pk1 = (__float_as_uint(acc1[i]) & 0xFFFFF800u) | lcol1;
            rowbest[i] = umin_(rowbest[i], umin_(pk0, pk1));                  // v_min3_u32
        }
        // col path: fmin tree over this lane's 16 rows, both halves atomicMin
        float c0 = fminf(fminf(fminf(fminf(acc0[0], acc0[1]), fminf(acc0[2], acc0[3])),
                               fminf(fminf(acc0[4], acc0[5]), fminf(acc0[6], acc0[7]))),
                         fminf(fminf(fminf(acc0[8], acc0[9]), fminf(acc0[10], acc0[11])),
                               fminf(fminf(acc0[12], acc0[13]), fminf(acc0[14], acc0[15]))));
        float c1 = fminf(fminf(fminf(fminf(acc1[0], acc1[1]), fminf(acc1[2], acc1[3])),
                               fminf(fminf(acc1[4], acc1[5]), fminf(acc1[6], acc1[7]))),
                         fminf(fminf(fminf(acc1[8], acc1[9]), fminf(acc1[10], acc1[11])),
                               fminf(fminf(acc1[12], acc1[13]), fminf(acc1[14], acc1[15]))));
        atomicMin(&ldsCol[lcol0], __float_as_uint(c0));
        atomicMin(&ldsCol[lcol1], __float_as_uint(c1));
    }

    // ---- row partials: min across the 32 lanes sharing each row, plain store
    unsigned long long* rdst = rowpart + (size_t)(b * COLSPLIT + cs) * M_;
    #pragma unroll
    for (int i = 0; i < 16; ++i) {
        unsigned pk = rowbest[i];
        #pragma unroll
        for (int off = 1; off < 32; off <<= 1) {
            unsigned o = __shfl_xor(pk, off);
            pk = o < pk ? o : pk;
        }
        if (l31 == 0) {
            int row = rowbase + (i & 3) + 8 * (i >> 2) + 4 * half;
            rdst[row] = ((unsigned long long)(pk & 0xFFFFF800u) << 32)
                        | (unsigned)(colbase + (pk & 0x7FFu));
        }
    }

    // ---- col finalization: global u32 atomicMin ----
    __syncthreads();
    #pragma unroll
    for (int i = t; i < CCHUNK; i += 256)
        atomicMin(&colminU[(size_t)b * N_ + colbase + i], ldsCol[i]);
}

// ---------------------------------------------------------------------------
// Combine row partials, read col mins, gather sdf/color at argmin, and
// accumulate the three outputs into d_out (zeroed by k_init) via 3
// atomicAdds per block. grid = 64 x 256 = B*M threads.
// ---------------------------------------------------------------------------
__global__ __launch_bounds__(256) void k_reduce(
    const unsigned long long* __restrict__ rowpart, // [B][COLSPLIT][M]
    const unsigned int* __restrict__ colminU,       // [B*N]
    const float* __restrict__ pred_sdfs,
    const float* __restrict__ pred_cols,
    const float* __restrict__ ref_sdfs,
    const float* __restrict__ ref_cols,
    float* __restrict__ out)   // [3]
{
    __shared__ float wsum[4][3];
    const int i = blockIdx.x * 256 + threadIdx.x;   // 0 .. B*M-1
    const int b = i >> 13;
    const int m = i & (M_ - 1);

    // row combine: 16 coalesced u64 reads (all L2-resident)
    unsigned long long pk = 0xFFFFFFFFFFFFFFFFull;
    #pragma unroll
    for (int s = 0; s < COLSPLIT; ++s)
        pk = ullmin_(pk, rowpart[(size_t)(b * COLSPLIT + s) * M_ + m]);

    unsigned cm = colminU[i];

    float chyx = fmaxf(__uint_as_float((unsigned)(pk >> 32)), 0.f);
    int arg = (int)(unsigned)(pk & 0xFFFFFFFFull);
    float chxy = fmaxf(__uint_as_float(cm), 0.f);

    float sdf = fabsf(ref_sdfs[(size_t)b * M_ + arg] - pred_sdfs[i]);
    const float* rc = ref_cols + ((size_t)b * M_ + arg) * 3;
    const float* pc = pred_cols + (size_t)i * 3;
    float col = fabsf(rc[0] - pc[0]) + fabsf(rc[1] - pc[1]) + fabsf(rc[2] - pc[2]);

    float cham = chyx * (1.f / (B_ * M_)) + chxy * (1.f / (B_ * N_));
    sdf *= 1.f / (B_ * M_);
    col *= 1.f / (B_ * M_ * 3);

    #pragma unroll
    for (int off = 32; off > 0; off >>= 1) {
        sdf  += __shfl_down(sdf, off);
        col  += __shfl_down(col, off);
        cham += __shfl_down(cham, off);
    }
    const int wave = threadIdx.x >> 6;
    if ((threadIdx.x & 63) == 0) {
        wsum[wave][0] = sdf; wsum[wave][1] = col; wsum[wave][2] = cham;
    }
    __syncthreads();
    if (threadIdx.x == 0) {
        atomicAdd(&out[0], wsum[0][0] + wsum[1][0] + wsum[2][0] + wsum[3][0]);
        atomicAdd(&out[1], wsum[0][1] + wsum[1][1] + wsum[2][1] + wsum[3][1]);
        atomicAdd(&out[2], wsum[0][2] + wsum[1][2] + wsum[2][2] + wsum[3][2]);
    }
}

extern "C" void kernel_launch(void* const* d_in, const int* in_sizes, int n_in,
                              void* d_out, int out_size, void* d_ws, size_t ws_size,
                              hipStream_t stream) {
    const float* pred_pts  = (const float*)d_in[0];
    const float* pred_sdfs = (const float*)d_in[1];
    const float* pred_cols = (const float*)d_in[2];
    const float* ref_pts   = (const float*)d_in[3];
    const float* ref_sdfs  = (const float*)d_in[4];
    const float* ref_cols  = (const float*)d_in[5];
    float* out = (float*)d_out;

    // ws layout: [rowpart u64 B*16*M = 2 MiB][colminU u32 B*N = 64 KiB]
    //            [predB uint4 B*N = 256 KiB][refA uint4 B*M = 256 KiB]
    char* ws = (char*)d_ws;
    unsigned long long* rowpart = (unsigned long long*)ws;
    unsigned int* colminU = (unsigned int*)(ws + (size_t)B_ * COLSPLIT * M_ * 8);
    uint4* predB = (uint4*)(ws + (size_t)B_ * COLSPLIT * M_ * 8 + (size_t)B_ * N_ * 4);
    uint4* refA  = predB + (size_t)B_ * N_;

    k_init<<<(B_ * N_) / 256, 256, 0, stream>>>(
        pred_pts, ref_pts, predB, refA, (uint4*)colminU, out);

    dim3 g1(ROWBLKS, COLSPLIT, B_);   // (64, 16, 2) = 2048 blocks
    k_pairs<<<g1, 256, 0, stream>>>(predB, refA, rowpart, colminU);

    k_reduce<<<RBLOCKS, 256, 0, stream>>>(
        rowpart, colminU, pred_sdfs, pred_cols, ref_sdfs, ref_cols, out);
}

// Round 9
// 89.983 us; speedup vs baseline: 1.0341x; 1.0341x over previous
//
#include <hip/hip_runtime.h>
#include <cstdint>
#include <cstddef>

// B=2, N=M=8192, 3-float points.
// R9 = exact revert to the best-measured variant (R5, 90.26 us).
// Session finding: five structural variants (R4-R8) all land 90.3-93.1 us;
// the timed window is dominated by harness d_ws re-poison (40 us @ 84% HBM
// peak) + fixed overheads; the kernel chain (~10-15 us) is below the
// round-to-round noise band, so measured-best wins over theory-best.
#define B_ 2
#define N_ 8192
#define M_ 8192
#define COLSPLIT 8
#define CCHUNK (N_ / COLSPLIT)      // 1024 cols per block
#define NTILES (CCHUNK / 32)        // 32 col tiles of 32
#define ROWS_PER_WAVE 32
#define ROWS_PER_BLOCK 128          // 4 waves
#define RBLOCKS ((B_ * M_) / 256)   // 64 reduce blocks

typedef __attribute__((ext_vector_type(8))) short short8;
typedef __attribute__((ext_vector_type(16))) float f32x16;

union FragU { uint4 u; short8 s; };

// round-to-nearest-even f32 -> bf16 bits
__device__ __forceinline__ unsigned bf16r(float f) {
    unsigned u = __float_as_uint(f);
    return ((u + 0x7FFFu + ((u >> 16) & 1u)) >> 16) & 0xFFFFu;
}
#define BF_ONE 0x3F80u

__device__ __forceinline__ unsigned umin_(unsigned a, unsigned b) { return a < b ? a : b; }

// ---------------------------------------------------------------------------
// Sentinel init for the atomicMin arrays (192 KiB = 12288 uint4).
// ---------------------------------------------------------------------------
__global__ __launch_bounds__(256) void k_init(uint4* __restrict__ p)
{
    const int i = blockIdx.x * 256 + threadIdx.x;   // 48 * 256 = 12288
    uint4 v = {0xFFFFFFFFu, 0xFFFFFFFFu, 0xFFFFFFFFu, 0xFFFFFFFFu};
    p[i] = v;
}

// ---------------------------------------------------------------------------
// MFMA pairwise-d2 kernel. D[m(ref) rows][n(pred) cols], both directions from
// one tile sweep. K-slot encoding puts |r|^2+|p|^2-2r.p inside the MFMA:
// A(ref)=[x,y,z,Nh,Nl,1,1,0], B(pred)=[-2x,-2y,-2z,1,1,Nh,Nl,0].
// 2 tiles per iteration (2 MFMAs in flight); row argmin via v_and_or_b32 pack
// + v_min3_u32; col min via in-lane fmin tree + LDS atomicMin from BOTH
// 32-lane halves (no per-tile shuffle in the dependent chain).
// grid = (M/128, COLSPLIT, B) = (64, 8, 2) = 1024 blocks, 4 waves/SIMD.
// ---------------------------------------------------------------------------
__global__ __launch_bounds__(256, 4) void k_pairs(
    const float* __restrict__ pred_pts,   // [B,N,3]
    const float* __restrict__ ref_pts,    // [B,M,3]
    unsigned long long* __restrict__ packed,  // [B*M], init 0xFF
    unsigned int* __restrict__ colminU)       // [B*N], init 0xFF
{
    __shared__ uint4 ldsB[CCHUNK + 1];        // [CCHUNK] is the zero slot
    __shared__ unsigned int ldsCol[CCHUNK];

    const int t    = threadIdx.x;
    const int wave = t >> 6;
    const int lane = t & 63;
    const int l31  = lane & 31;
    const int half = lane >> 5;
    const int rowblk  = blockIdx.x;
    const int colbase = blockIdx.y * CCHUNK;
    const int b       = blockIdx.z;

    // ---- stage pred-point B-vectors into LDS ----
    for (int i = t; i < CCHUNK; i += 256) {
        const float* p = pred_pts + ((size_t)b * N_ + colbase + i) * 3;
        float x = p[0], y = p[1], z = p[2];
        float nrm = x * x + y * y + z * z;
        unsigned nh = bf16r(nrm);
        unsigned nl = bf16r(nrm - __uint_as_float(nh << 16));
        uint4 v;
        v.x = bf16r(-2.f * x) | (bf16r(-2.f * y) << 16);
        v.y = bf16r(-2.f * z) | (BF_ONE << 16);
        v.z = BF_ONE | (nh << 16);
        v.w = nl;                              // slot7 = 0
        ldsB[i] = v;
        ldsCol[i] = 0xFFFFFFFFu;
    }
    if (t == 0) { uint4 z4 = {0, 0, 0, 0}; ldsB[CCHUNK] = z4; }

    // ---- A frag (ref points); lanes >= 32 hold the zero K-half ----
    FragU af; af.u.x = af.u.y = af.u.z = af.u.w = 0;
    const int rowbase = rowblk * ROWS_PER_BLOCK + wave * ROWS_PER_WAVE;
    if (half == 0) {
        const float* r = ref_pts + ((size_t)b * M_ + rowbase + l31) * 3;
        float x = r[0], y = r[1], z = r[2];
        float nrm = x * x + y * y + z * z;
        unsigned nh = bf16r(nrm);
        unsigned nl = bf16r(nrm - __uint_as_float(nh << 16));
        af.u.x = bf16r(x) | (bf16r(y) << 16);
        af.u.y = bf16r(z) | (nh << 16);
        af.u.z = nl | (BF_ONE << 16);
        af.u.w = BF_ONE;                       // slot7 = 0
    }
    __syncthreads();

    f32x16 zero16 = {};
    unsigned rowbest[16];
    #pragma unroll
    for (int i = 0; i < 16; ++i) rowbest[i] = 0xFFFFFFFFu;

    const int bslot = (half == 0) ? l31 : CCHUNK;   // zero slot for hi half
    const int bstep = (half == 0) ? 32 : 0;

    #pragma unroll 2
    for (int tile = 0; tile < NTILES; tile += 2) {
        FragU b0; b0.u = ldsB[bslot + tile * bstep];
        FragU b1; b1.u = ldsB[bslot + (tile + 1) * bstep];
        f32x16 acc0 = __builtin_amdgcn_mfma_f32_32x32x16_bf16(af.s, b0.s, zero16, 0, 0, 0);
        f32x16 acc1 = __builtin_amdgcn_mfma_f32_32x32x16_bf16(af.s, b1.s, zero16, 0, 0, 0);

        const unsigned lcol0 = (unsigned)(tile * 32 + l31);
        const unsigned lcol1 = lcol0 + 32;
        #pragma unroll
        for (int i = 0; i < 16; ++i) {
            unsigned pk0 = (__float_as_uint(acc0[i]) & 0xFFFFF800u) | lcol0;  // v_and_or_b32
            unsigned pk1 = (__float_as_uint(acc1[i]) & 0xFFFFF800u) | lcol1;
            rowbest[i] = umin_(rowbest[i], umin_(pk0, pk1));                  // v_min3_u32
        }
        // col path: fmin tree over this lane's 16 rows, both halves atomicMin
        float c0 = fminf(fminf(fminf(fminf(acc0[0], acc0[1]), fminf(acc0[2], acc0[3])),
                               fminf(fminf(acc0[4], acc0[5]), fminf(acc0[6], acc0[7]))),
                         fminf(fminf(fminf(acc0[8], acc0[9]), fminf(acc0[10], acc0[11])),
                               fminf(fminf(acc0[12], acc0[13]), fminf(acc0[14], acc0[15]))));
        float c1 = fminf(fminf(fminf(fminf(acc1[0], acc1[1]), fminf(acc1[2], acc1[3])),
                               fminf(fminf(acc1[4], acc1[5]), fminf(acc1[6], acc1[7]))),
                         fminf(fminf(fminf(acc1[8], acc1[9]), fminf(acc1[10], acc1[11])),
                               fminf(fminf(acc1[12], acc1[13]), fminf(acc1[14], acc1[15]))));
        atomicMin(&ldsCol[lcol0], __float_as_uint(c0));
        atomicMin(&ldsCol[lcol1], __float_as_uint(c1));
    }

    // ---- row finalization: min across the 32 lanes sharing each row ----
    #pragma unroll
    for (int i = 0; i < 16; ++i) {
        unsigned pk = rowbest[i];
        #pragma unroll
        for (int off = 1; off < 32; off <<= 1) {
            unsigned o = __shfl_xor(pk, off);
            pk = o < pk ? o : pk;
        }
        if (l31 == 0) {
            int row = rowbase + (i & 3) + 8 * (i >> 2) + 4 * half;
            unsigned long long v =
                ((unsigned long long)(pk & 0xFFFFF800u) << 32)
                | (unsigned)(colbase + (pk & 0x7FFu));
            atomicMin(&packed[(size_t)b * M_ + row], v);
        }
    }

    // ---- col finalization ----
    __syncthreads();
    for (int i = t; i < CCHUNK; i += 256)
        atomicMin(&colminU[(size_t)b * N_ + colbase + i], ldsCol[i]);
}

// ---------------------------------------------------------------------------
// Gather + per-block partials (plain stores; no d_out zeroing needed).
// ---------------------------------------------------------------------------
__global__ __launch_bounds__(256) void k_reduce(
    const unsigned long long* __restrict__ packed,  // [B*M]
    const unsigned int* __restrict__ colminU,       // [B*N]
    const float* __restrict__ pred_sdfs,
    const float* __restrict__ pred_cols,
    const float* __restrict__ ref_sdfs,
    const float* __restrict__ ref_cols,
    float* __restrict__ partials)   // [3][RBLOCKS]
{
    __shared__ float wsum[4][3];
    const int i = blockIdx.x * 256 + threadIdx.x;   // 0 .. B*M-1
    const int b = i >> 13;

    unsigned long long pk = packed[i];
    float chyx = fmaxf(__uint_as_float((unsigned)(pk >> 32)), 0.f);
    int arg = (int)(unsigned)(pk & 0xFFFFFFFFull);
    float chxy = fmaxf(__uint_as_float(colminU[i]), 0.f);

    float sdf = fabsf(ref_sdfs[(size_t)b * M_ + arg] - pred_sdfs[i]);
    const float* rc = ref_cols + ((size_t)b * M_ + arg) * 3;
    const float* pc = pred_cols + (size_t)i * 3;
    float col = fabsf(rc[0] - pc[0]) + fabsf(rc[1] - pc[1]) + fabsf(rc[2] - pc[2]);

    float cham = chyx * (1.f / (B_ * M_)) + chxy * (1.f / (B_ * N_));
    sdf *= 1.f / (B_ * M_);
    col *= 1.f / (B_ * M_ * 3);

    #pragma unroll
    for (int off = 32; off > 0; off >>= 1) {
        sdf  += __shfl_down(sdf, off);
        col  += __shfl_down(col, off);
        cham += __shfl_down(cham, off);
    }
    const int wave = threadIdx.x >> 6;
    if ((threadIdx.x & 63) == 0) {
        wsum[wave][0] = sdf; wsum[wave][1] = col; wsum[wave][2] = cham;
    }
    __syncthreads();
    if (threadIdx.x == 0) {
        partials[0 * RBLOCKS + blockIdx.x] = wsum[0][0] + wsum[1][0] + wsum[2][0] + wsum[3][0];
        partials[1 * RBLOCKS + blockIdx.x] = wsum[0][1] + wsum[1][1] + wsum[2][1] + wsum[3][1];
        partials[2 * RBLOCKS + blockIdx.x] = wsum[0][2] + wsum[1][2] + wsum[2][2] + wsum[3][2];
    }
}

__global__ void k_final(const float* __restrict__ partials, float* __restrict__ out)
{
    const int t = threadIdx.x;    // 64 threads
    float s0 = partials[0 * RBLOCKS + t];
    float s1 = partials[1 * RBLOCKS + t];
    float s2 = partials[2 * RBLOCKS + t];
    #pragma unroll
    for (int off = 32; off > 0; off >>= 1) {
        s0 += __shfl_down(s0, off);
        s1 += __shfl_down(s1, off);
        s2 += __shfl_down(s2, off);
    }
    if (t == 0) { out[0] = s0; out[1] = s1; out[2] = s2; }
}

extern "C" void kernel_launch(void* const* d_in, const int* in_sizes, int n_in,
                              void* d_out, int out_size, void* d_ws, size_t ws_size,
                              hipStream_t stream) {
    const float* pred_pts  = (const float*)d_in[0];
    const float* pred_sdfs = (const float*)d_in[1];
    const float* pred_cols = (const float*)d_in[2];
    const float* ref_pts   = (const float*)d_in[3];
    const float* ref_sdfs  = (const float*)d_in[4];
    const float* ref_cols  = (const float*)d_in[5];
    float* out = (float*)d_out;

    // ws layout: [packed u64 B*M =128KiB][colminU u32 B*N =64KiB][partials 3*64 f32]
    char* ws = (char*)d_ws;
    unsigned long long* packed = (unsigned long long*)ws;
    unsigned int* colminU = (unsigned int*)(ws + (size_t)B_ * M_ * 8);
    float* partials = (float*)(ws + (size_t)B_ * M_ * 8 + (size_t)B_ * N_ * 4);

    k_init<<<48, 256, 0, stream>>>((uint4*)ws);

    dim3 g1(M_ / ROWS_PER_BLOCK, COLSPLIT, B_);   // (64, 8, 2) = 1024 blocks
    k_pairs<<<g1, 256, 0, stream>>>(pred_pts, ref_pts, packed, colminU);

    k_reduce<<<RBLOCKS, 256, 0, stream>>>(
        packed, colminU, pred_sdfs, pred_cols, ref_sdfs, ref_cols, partials);

    k_final<<<1, 64, 0, stream>>>(partials, out);
}